// Round 1
// baseline (215.017 us; speedup 1.0000x reference)
//
#include <hip/hip_runtime.h>
#include <math.h>

#define NRES 384
#define NH   12
#define WLc 0.5773502691896258f
#define WCc 0.23570226039551587f

typedef __attribute__((ext_vector_type(8))) _Float16 half8;
typedef __attribute__((ext_vector_type(2))) _Float16 half2v;
typedef __attribute__((ext_vector_type(4))) float f32x4;

// workspace layout (float offsets), lifetime-overlaid:
#define OFF_P    0          // f32 [384][1152] proj out (dead after prep)
#define OFF_SH   442368     // f16 [384][384] s (dead after proj)
#define OFF_WCT  516096     // f16 [1152][384] Wcat^T (dead after proj)
#define OFF_BCT  737280     // f32 [1152]
#define OFF_QE   738432     // f32 [384][384] (i, h*32+c)
#define OFF_KE   885888     // f32 [12][384][32]
#define OFF_VET  1033344    // f16 [12][48][384]
#define OFF_WOT  1143936    // f16 [384][2112] Wo^T
#define OFF_CAT  1549440    // f16 [384][2112] unified concat (cols 0..575 from K3, 576..2111 from K4)
#define OFF_ATT  1954944    // f16 [12][384][384] att
#define OFF_BIAS 2839680    // f16 [12][384][384] wl*(z@Wb+bb)
// end 3724416 floats = 14.9 MB

// ---------------------------------------------------------------------------
// K0: pack + bias. Blocks 0..450: s->f16, Wcat^T, Wo^T, bcat.
// Blocks 451..2754: bias MFMA with direct-global z A-fragments.
// ---------------------------------------------------------------------------
__global__ __launch_bounds__(256) void pack_bias(
    const float* __restrict__ s,  const float* __restrict__ z,
    const float* __restrict__ Wq,  const float* __restrict__ bq,
    const float* __restrict__ Wk,  const float* __restrict__ bk,
    const float* __restrict__ Wv,  const float* __restrict__ bv,
    const float* __restrict__ Wqp, const float* __restrict__ bqp,
    const float* __restrict__ Wkp, const float* __restrict__ bkp,
    const float* __restrict__ Wvp, const float* __restrict__ bvp,
    const float* __restrict__ Wb,  const float* __restrict__ bb,
    const float* __restrict__ Wo,
    float* __restrict__ ws)
{
    int b = blockIdx.x, t = threadIdx.x;
    __shared__ float tile[64 * 65];
    __shared__ _Float16 wbT[16 * 136];
    __shared__ float sbb[16];

    if (b >= 451) {                         // ---- bias MFMA (2304 blocks) ----
        _Float16* biasb = (_Float16*)(ws + OFF_BIAS);
        int bi = b - 451;
        size_t m0 = (size_t)bi * 64;
        if (t < 128) {
            #pragma unroll
            for (int h = 0; h < 12; h++) wbT[h * 136 + t] = (_Float16)(WLc * Wb[t * 12 + h]);
            #pragma unroll
            for (int h = 12; h < 16; h++) wbT[h * 136 + t] = (_Float16)0.f;
        }
        if (t < 16) sbb[t] = (t < 12) ? WLc * bb[t] : 0.f;
        __syncthreads();
        int w = t >> 6, lane = t & 63;
        int m = lane & 15, q = lane >> 4;
        size_t ri = m0 + w * 16 + m;
        const float* zr = z + ri * 128 + q * 8;
        f32x4 acc = {0};
        #pragma unroll
        for (int sI = 0; sI < 4; sI++) {
            float4 v0 = *(const float4*)(zr + sI * 32);
            float4 v1 = *(const float4*)(zr + sI * 32 + 4);
            half8 a;
            a[0]=(_Float16)v0.x; a[1]=(_Float16)v0.y; a[2]=(_Float16)v0.z; a[3]=(_Float16)v0.w;
            a[4]=(_Float16)v1.x; a[5]=(_Float16)v1.y; a[6]=(_Float16)v1.z; a[7]=(_Float16)v1.w;
            half8 bf = *(const half8*)(wbT + m * 136 + sI * 32 + q * 8);
            acc = __builtin_amdgcn_mfma_f32_16x16x32_f16(a, bf, acc, 0, 0, 0);
        }
        if (m < 12) {
            #pragma unroll
            for (int r = 0; r < 4; r++)
                biasb[(size_t)m * 147456 + m0 + w * 16 + q * 4 + r] = (_Float16)(acc[r] + sbb[m]);
        }
        return;
    }

    _Float16* sh  = (_Float16*)(ws + OFF_SH);
    _Float16* wct = (_Float16*)(ws + OFF_WCT);
    _Float16* wot = (_Float16*)(ws + OFF_WOT);
    float* bct = ws + OFF_BCT;

    if (b < 144) {                          // s -> f16
        int id = b * 256 + t;
        float4 v = ((const float4*)s)[id];
        _Float16 r[4] = { (_Float16)v.x, (_Float16)v.y, (_Float16)v.z, (_Float16)v.w };
        *(uint2*)(sh + id * 4) = *(uint2*)r;
        return;
    }
    if (b < 252) {                          // Wcat^T tiles (108)
        int ti = b - 144;
        int k0 = (ti % 6) * 64, n0 = (ti / 6) * 64;
        int cl = t & 63, rg = t >> 6;
        int ncat = n0 + cl;
        const float* W; int dout, col;
        if      (ncat < 192) { W = Wq;  dout = 192; col = ncat; }
        else if (ncat < 384) { W = Wk;  dout = 192; col = ncat - 192; }
        else if (ncat < 576) { W = Wv;  dout = 192; col = ncat - 384; }
        else if (ncat < 720) { W = Wqp; dout = 144; col = ncat - 576; }
        else if (ncat < 864) { W = Wkp; dout = 144; col = ncat - 720; }
        else                 { W = Wvp; dout = 288; col = ncat - 864; }
        #pragma unroll
        for (int u = 0; u < 16; u++) {
            int r = rg * 16 + u;
            tile[r * 65 + cl] = W[(size_t)(k0 + r) * dout + col];
        }
        __syncthreads();
        #pragma unroll
        for (int u2 = 0; u2 < 2; u2++) {
            int item = t + 256 * u2;
            int nl = item >> 3, kg = item & 7;
            half8 rr;
            #pragma unroll
            for (int jj = 0; jj < 8; jj++) rr[jj] = (_Float16)tile[(kg * 8 + jj) * 65 + nl];
            *(half8*)(wct + (size_t)(n0 + nl) * 384 + k0 + kg * 8) = rr;
        }
        return;
    }
    if (b < 450) {                          // Wo^T tiles (198)
        int ti = b - 252;
        int k0 = (ti % 33) * 64, n0 = (ti / 33) * 64;
        int cl = t & 63, rg = t >> 6;
        #pragma unroll
        for (int u = 0; u < 16; u++) {
            int r = rg * 16 + u;
            tile[r * 65 + cl] = Wo[(size_t)(k0 + r) * 384 + n0 + cl];
        }
        __syncthreads();
        #pragma unroll
        for (int u2 = 0; u2 < 2; u2++) {
            int item = t + 256 * u2;
            int nl = item >> 3, kg = item & 7;
            half8 rr;
            #pragma unroll
            for (int jj = 0; jj < 8; jj++) rr[jj] = (_Float16)tile[(kg * 8 + jj) * 65 + nl];
            *(half8*)(wot + (size_t)(n0 + nl) * 2112 + k0 + kg * 8) = rr;
        }
        return;
    }
    // b == 450: bcat
    for (int e = t; e < 1152; e += 256) {
        float bv_;
        if      (e < 192) bv_ = bq[e];
        else if (e < 384) bv_ = bk[e - 192];
        else if (e < 576) bv_ = bv[e - 384];
        else if (e < 720) bv_ = bqp[e - 576];
        else if (e < 864) bv_ = bkp[e - 720];
        else              bv_ = bvp[e - 864];
        bct[e] = bv_;
    }
}

// ---------------------------------------------------------------------------
// K1: proj MFMA (f16): P(384x1152) = s @ Wcat + bcat. grid (18,12) x 256.
// 4 waves: (mh = w&1) m-subtile, (kh = w>>1) k-half; LDS combine.
// ---------------------------------------------------------------------------
__global__ __launch_bounds__(256) void proj_mfma(float* __restrict__ ws)
{
    const _Float16* sh  = (const _Float16*)(ws + OFF_SH);
    const _Float16* wct = (const _Float16*)(ws + OFF_WCT);
    const float* bct = ws + OFF_BCT;
    float* P = ws + OFF_P;

    __shared__ float sAcc[2][16][65];

    int t = threadIdx.x, w = t >> 6, lane = t & 63;
    int m = lane & 15, q = lane >> 4;
    int mh = w & 1, kh = w >> 1;
    int n0 = blockIdx.x * 64, m0 = blockIdx.y * 32 + mh * 16;

    f32x4 acc[4] = {0};
    const _Float16* arow = sh + (size_t)(m0 + m) * 384 + kh * 192;
    #pragma unroll 3
    for (int s = 0; s < 6; s++) {
        int k = s * 32 + q * 8;
        half8 a = *(const half8*)(arow + k);
        #pragma unroll
        for (int nt = 0; nt < 4; nt++) {
            half8 b = *(const half8*)(wct + (size_t)(n0 + nt * 16 + m) * 384 + kh * 192 + k);
            acc[nt] = __builtin_amdgcn_mfma_f32_16x16x32_f16(a, b, acc[nt], 0, 0, 0);
        }
    }
    if (kh == 0) {
        #pragma unroll
        for (int nt = 0; nt < 4; nt++)
            #pragma unroll
            for (int r = 0; r < 4; r++)
                sAcc[mh][q * 4 + r][nt * 16 + m] = acc[nt][r];
    }
    __syncthreads();
    if (kh == 1) {
        #pragma unroll
        for (int nt = 0; nt < 4; nt++) {
            int col = n0 + nt * 16 + m;
            float bias = bct[col];
            #pragma unroll
            for (int r = 0; r < 4; r++)
                P[(size_t)(m0 + q * 4 + r) * 1152 + col] =
                    acc[nt][r] + sAcc[mh][q * 4 + r][nt * 16 + m] + bias;
        }
    }
}

// ---------------------------------------------------------------------------
// K2: prep — per-i block. Qe[i][h*32+c] f32, Ke[h][i][32] f32, Ve_t f16
// ---------------------------------------------------------------------------
__global__ __launch_bounds__(192) void prep_kernel(
    const float* __restrict__ T, const float* __restrict__ hw,
    float* __restrict__ ws)
{
    int i = blockIdx.x, t = threadIdx.x;
    const float* pr = ws + OFF_P + (size_t)i * 1152;
    float* Qe = ws + OFF_QE;
    float* Ke = ws + OFF_KE;
    _Float16* vet = (_Float16*)(ws + OFF_VET);

    __shared__ float sT[16], sG[12];
    __shared__ float sTQ[12][4][3], sTK[12][4][3];
    if (t < 16) sT[t] = T[i * 16 + t];
    if (t < 12) { float x = hw[t]; sG[t] = (x > 20.f) ? x : log1pf(__expf(x)); }
    __syncthreads();
    float R00=sT[0],R01=sT[1],R02=sT[2],t0=sT[3];
    float R10=sT[4],R11=sT[5],R12=sT[6],t1=sT[7];
    float R20=sT[8],R21=sT[9],R22=sT[10],t2=sT[11];

    if (t < 48) {
        int h = t >> 2, p = t & 3;
        float a0 = pr[576 + 0*48 + h*4 + p], a1 = pr[576 + 1*48 + h*4 + p], a2 = pr[576 + 2*48 + h*4 + p];
        sTQ[h][p][0] = R00*a0 + R01*a1 + R02*a2 + t0;
        sTQ[h][p][1] = R10*a0 + R11*a1 + R12*a2 + t1;
        sTQ[h][p][2] = R20*a0 + R21*a1 + R22*a2 + t2;
    } else if (t < 96) {
        int tt = t - 48, h = tt >> 2, p = tt & 3;
        float a0 = pr[720 + 0*48 + h*4 + p], a1 = pr[720 + 1*48 + h*4 + p], a2 = pr[720 + 2*48 + h*4 + p];
        sTK[h][p][0] = R00*a0 + R01*a1 + R02*a2 + t0;
        sTK[h][p][1] = R10*a0 + R11*a1 + R12*a2 + t1;
        sTK[h][p][2] = R20*a0 + R21*a1 + R22*a2 + t2;
    } else {
        int tt = t - 96, h = tt >> 3, p = tt & 7;
        float a0 = pr[864 + 0*96 + h*8 + p], a1 = pr[864 + 1*96 + h*8 + p], a2 = pr[864 + 2*96 + h*8 + p];
        vet[(size_t)(h*48 + 16 + p*3 + 0) * 384 + i] = (_Float16)(R00*a0 + R01*a1 + R02*a2 + t0);
        vet[(size_t)(h*48 + 16 + p*3 + 1) * 384 + i] = (_Float16)(R10*a0 + R11*a1 + R12*a2 + t1);
        vet[(size_t)(h*48 + 16 + p*3 + 2) * 384 + i] = (_Float16)(R20*a0 + R21*a1 + R22*a2 + t2);
    }
    {
        int h = t >> 4, c = t & 15;
        vet[(size_t)(h*48 + c) * 384 + i] = (_Float16)pr[384 + h*16 + c];
        if (t < 96) vet[(size_t)((t>>3)*48 + 40 + (t&7)) * 384 + i] = (_Float16)0.f;
        Qe[(size_t)i*384 + h*32 + c] = WLc * 0.25f * pr[h*16 + c];
        Ke[((size_t)h*384 + i)*32 + c] = pr[192 + h*16 + c];
    }
    __syncthreads();
    if (t < 144) {
        int h = t / 12, d = t % 12, p = d / 3, r = d % 3;
        float gw = WLc * sG[h] * WCc;
        Qe[(size_t)i*384 + h*32 + 16 + d] = gw * sTQ[h][p][r];
        Ke[((size_t)h*384 + i)*32 + 16 + d] = sTK[h][p][r];
    }
    if (t < 12) {
        int h = t;
        float sqq = 0.f, sqk = 0.f;
        #pragma unroll
        for (int p = 0; p < 4; p++)
            #pragma unroll
            for (int r = 0; r < 3; r++) { sqq += sTQ[h][p][r]*sTQ[h][p][r]; sqk += sTK[h][p][r]*sTK[h][p][r]; }
        float gw = WLc * sG[h] * WCc;
        Qe[(size_t)i*384 + h*32 + 28] = -0.5f * gw;
        Qe[(size_t)i*384 + h*32 + 29] = -0.5f * gw * sqq;
        Qe[(size_t)i*384 + h*32 + 30] = 0.f;
        Qe[(size_t)i*384 + h*32 + 31] = 0.f;
        Ke[((size_t)h*384 + i)*32 + 28] = sqk;
        Ke[((size_t)h*384 + i)*32 + 29] = 1.f;
        Ke[((size_t)h*384 + i)*32 + 30] = 0.f;
        Ke[((size_t)h*384 + i)*32 + 31] = 0.f;
    }
}

// ---------------------------------------------------------------------------
// K3: logits + softmax + out40 + epilogue. grid (48 i-tiles, 12 h) x 512.
// (chore phase removed: no out preset, no PW zero — K5 writes out directly)
// ---------------------------------------------------------------------------
__global__ __launch_bounds__(512) void logits_out40(
    const float* __restrict__ T, float* __restrict__ ws)
{
    __shared__ float sQe[8 * 32];
    __shared__ float sLg[8][384];
    __shared__ float sMS[16];
    __shared__ _Float16 sAttL[8 * 392];
    __shared__ float sO[8 * 49];
    __shared__ float sT8[8 * 16];

    int h = blockIdx.y, i0 = blockIdx.x * 8;
    int t = threadIdx.x;
    const float* Qe = ws + OFF_QE;
    const float* Ke = ws + OFF_KE;
    const _Float16* biasb = (const _Float16*)(ws + OFF_BIAS);
    const _Float16* vet = (const _Float16*)(ws + OFF_VET);
    _Float16* attg = (_Float16*)(ws + OFF_ATT);
    _Float16* catb = (_Float16*)(ws + OFF_CAT);

    if (t < 256)
        sQe[t] = Qe[(size_t)(i0 + (t >> 5)) * 384 + h * 32 + (t & 31)];
    if (t < 128)
        sT8[t] = T[(size_t)(i0 + (t >> 4)) * 16 + (t & 15)];
    __syncthreads();

    float lgv[8];
    if (t < 384) {
        int j = t;
        float ke[32];
        const float4* kr = (const float4*)(Ke + ((size_t)h * 384 + j) * 32);
        #pragma unroll
        for (int u = 0; u < 8; u++) { float4 v = kr[u]; ke[u*4]=v.x; ke[u*4+1]=v.y; ke[u*4+2]=v.z; ke[u*4+3]=v.w; }
        #pragma unroll
        for (int ii = 0; ii < 8; ii++) {
            float acc = (float)biasb[(size_t)h * 147456 + (size_t)(i0 + ii) * 384 + j];
            #pragma unroll
            for (int c = 0; c < 32; c++) acc += sQe[ii * 32 + c] * ke[c];
            lgv[ii] = acc;
            sLg[ii][j] = acc;
        }
    }
    __syncthreads();
    {
        int w = t >> 6, lane = t & 63;
        float vv[6], mx = -1e30f;
        #pragma unroll
        for (int u = 0; u < 6; u++) { vv[u] = sLg[w][lane + 64 * u]; mx = fmaxf(mx, vv[u]); }
        #pragma unroll
        for (int off = 1; off < 64; off <<= 1) mx = fmaxf(mx, __shfl_xor(mx, off));
        float sm = 0.f;
        #pragma unroll
        for (int u = 0; u < 6; u++) sm += __expf(vv[u] - mx);
        #pragma unroll
        for (int off = 1; off < 64; off <<= 1) sm += __shfl_xor(sm, off);
        if (lane == 0) { sMS[w] = mx; sMS[8 + w] = sm; }
    }
    __syncthreads();
    if (t < 384) {
        int j = t;
        #pragma unroll
        for (int ii = 0; ii < 8; ii++) {
            float a = __expf(lgv[ii] - sMS[ii]) * (1.0f / sMS[8 + ii]);
            attg[((size_t)h * 384 + i0 + ii) * 384 + j] = (_Float16)a;
            sAttL[ii * 392 + j] = (_Float16)a;
        }
    }
    __syncthreads();

    // out40 GEMM: waves 0..2 each take one 16-wide n-tile of Ve (48 cols)
    int w = t >> 6, lane = t & 63;
    int m16 = lane & 15, q = lane >> 4;
    if (w < 3) {
        int nt = w;
        f32x4 acc = {0};
        #pragma unroll 3
        for (int s = 0; s < 12; s++) {
            int k = s * 32 + q * 8;
            half8 a;
            if (m16 < 8) a = *(const half8*)(sAttL + m16 * 392 + k);
            else         a = (half8){0,0,0,0,0,0,0,0};
            half8 bfr = *(const half8*)(vet + (size_t)(h * 48 + nt * 16 + m16) * 384 + k);
            acc = __builtin_amdgcn_mfma_f32_16x16x32_f16(a, bfr, acc, 0, 0, 0);
        }
        #pragma unroll
        for (int r = 0; r < 4; r++) {
            int row = q * 4 + r;
            if (row < 8) sO[row * 49 + nt * 16 + m16] = acc[r];
        }
    }
    __syncthreads();

    if (t < 128) {   // v_out -> cat cols h*16..h*16+15
        int il = t >> 4, c = t & 15;
        catb[(size_t)(i0 + il) * 2112 + h * 16 + c] = (_Float16)sO[il * 49 + c];
    }
    if (t < 64) {    // points + norm
        int il = t >> 3, p = t & 7;
        const float* o = sO + il * 49 + 16 + p * 3;
        const float* Ti = sT8 + il * 16;
        float x0 = o[0] - Ti[3], x1 = o[1] - Ti[7], x2 = o[2] - Ti[11];
        float r0 = Ti[0]*x0 + Ti[4]*x1 + Ti[8]*x2;
        float r1 = Ti[1]*x0 + Ti[5]*x1 + Ti[9]*x2;
        float r2 = Ti[2]*x0 + Ti[6]*x1 + Ti[10]*x2;
        _Float16* cr = catb + (size_t)(i0 + il) * 2112;
        cr[192 + 0*96 + h*8 + p] = (_Float16)r0;
        cr[192 + 1*96 + h*8 + p] = (_Float16)r1;
        cr[192 + 2*96 + h*8 + p] = (_Float16)r2;
        cr[480 + h*8 + p] = (_Float16)sqrtf(r0*r0 + r1*r1 + r2*r2);
    }
}

// ---------------------------------------------------------------------------
// K4: pairwise MFMA, no atomics: one block per i loops all 3 j-chunks,
// accumulates in registers, writes f16 directly into cat cols 576..2111.
// grid 384 x 256. z staged [c][j] f16 LDS via float4 loads + paired b32 writes.
// ---------------------------------------------------------------------------
__global__ __launch_bounds__(256) void pairwise_mfma(
    const float* __restrict__ z, float* __restrict__ ws)
{
    __shared__ _Float16 ztT[128 * 136];   // [c][j-chunk]
    __shared__ __attribute__((aligned(16))) _Float16 sPW[1536];
    int i = blockIdx.x;
    int t = threadIdx.x, w = t >> 6, lane = t & 63;
    int m16 = lane & 15, q = lane >> 4;
    const _Float16* attg = (const _Float16*)(ws + OFF_ATT);
    _Float16* catb = (_Float16*)(ws + OFF_CAT);

    f32x4 acc0 = {0}, acc1 = {0};
    const _Float16* arow = attg + ((size_t)(m16 < 12 ? m16 : 0) * 384 + i) * 384;

    int cq = t & 31, g = t >> 5;          // c-quad (0..31), j-group (0..7)
    for (int jc = 0; jc < 3; jc++) {
        if (jc) __syncthreads();          // prev chunk's MFMA reads done
        const float* zb = z + ((size_t)i * 384 + jc * 128) * 128;
        #pragma unroll
        for (int jp = 0; jp < 8; jp++) {
            int j = g * 16 + jp * 2;
            float4 v0 = *(const float4*)(zb + (size_t)j * 128 + cq * 4);
            float4 v1 = *(const float4*)(zb + (size_t)(j + 1) * 128 + cq * 4);
            half2v c0 = {(_Float16)v0.x, (_Float16)v1.x};
            half2v c1 = {(_Float16)v0.y, (_Float16)v1.y};
            half2v c2 = {(_Float16)v0.z, (_Float16)v1.z};
            half2v c3 = {(_Float16)v0.w, (_Float16)v1.w};
            *(half2v*)(ztT + (cq * 4 + 0) * 136 + j) = c0;
            *(half2v*)(ztT + (cq * 4 + 1) * 136 + j) = c1;
            *(half2v*)(ztT + (cq * 4 + 2) * 136 + j) = c2;
            *(half2v*)(ztT + (cq * 4 + 3) * 136 + j) = c3;
        }
        __syncthreads();
        #pragma unroll
        for (int ks = 0; ks < 4; ks++) {
            int k = ks * 32 + q * 8;
            half8 a;
            if (m16 < 12) a = *(const half8*)(arow + jc * 128 + k);
            else          a = (half8){0,0,0,0,0,0,0,0};
            half8 b0 = *(const half8*)(ztT + (w * 32 + m16) * 136 + k);
            half8 b1 = *(const half8*)(ztT + (w * 32 + 16 + m16) * 136 + k);
            acc0 = __builtin_amdgcn_mfma_f32_16x16x32_f16(a, b0, acc0, 0, 0, 0);
            acc1 = __builtin_amdgcn_mfma_f32_16x16x32_f16(a, b1, acc1, 0, 0, 0);
        }
    }
    if (q < 3) {
        #pragma unroll
        for (int r = 0; r < 4; r++) {
            int h = q * 4 + r;
            sPW[h * 128 + w * 32 + m16]      = (_Float16)acc0[r];
            sPW[h * 128 + w * 32 + 16 + m16] = (_Float16)acc1[r];
        }
    }
    __syncthreads();
    if (t < 192)      // coalesced half8 row write: cat cols 576..2111
        *(half8*)(catb + (size_t)i * 2112 + 576 + t * 8) = *(const half8*)(sPW + t * 8);
}

// ---------------------------------------------------------------------------
// K5: out GEMM, no atomics: out = cat(f16 [384][2112]) @ Wo + bo.
// grid (6 nt, 12 mt) x 256: 4 waves = (mh = w&1) x (kh = w>>1), LDS combine.
// ---------------------------------------------------------------------------
__global__ __launch_bounds__(256) void outgemm_mfma(
    float* __restrict__ ws, const float* __restrict__ bo, float* __restrict__ out)
{
    const _Float16* catb = (const _Float16*)(ws + OFF_CAT);
    const _Float16* wot = (const _Float16*)(ws + OFF_WOT);

    __shared__ float sAcc[2][16][65];

    int t = threadIdx.x, w = t >> 6, lane = t & 63;
    int m = lane & 15, q = lane >> 4;
    int mh = w & 1, kh = w >> 1;
    int n0 = blockIdx.x * 64;
    int m0 = blockIdx.y * 32 + mh * 16;

    f32x4 acc[4] = {0};
    int row = m0 + m;
    const _Float16* ar = catb + (size_t)row * 2112 + kh * 1056;
    #pragma unroll 3
    for (int s = 0; s < 33; s++) {
        int k = s * 32 + q * 8;
        half8 a = *(const half8*)(ar + k);
        #pragma unroll
        for (int nt = 0; nt < 4; nt++) {
            half8 b = *(const half8*)(wot + (size_t)(n0 + nt * 16 + m) * 2112 + kh * 1056 + k);
            acc[nt] = __builtin_amdgcn_mfma_f32_16x16x32_f16(a, b, acc[nt], 0, 0, 0);
        }
    }
    if (kh == 0) {
        #pragma unroll
        for (int nt = 0; nt < 4; nt++)
            #pragma unroll
            for (int r = 0; r < 4; r++)
                sAcc[mh][q * 4 + r][nt * 16 + m] = acc[nt][r];
    }
    __syncthreads();
    if (kh == 1) {
        #pragma unroll
        for (int nt = 0; nt < 4; nt++) {
            int col = n0 + nt * 16 + m;
            float bv = bo[col];
            #pragma unroll
            for (int r = 0; r < 4; r++)
                out[(size_t)(m0 + q * 4 + r) * 384 + col] =
                    acc[nt][r] + sAcc[mh][q * 4 + r][nt * 16 + m] + bv;
        }
    }
}

extern "C" void kernel_launch(void* const* d_in, const int* in_sizes, int n_in,
                              void* d_out, int out_size, void* d_ws, size_t ws_size,
                              hipStream_t stream)
{
    const float* s   = (const float*)d_in[0];
    const float* z   = (const float*)d_in[1];
    const float* T   = (const float*)d_in[2];
    const float* Wq  = (const float*)d_in[3];
    const float* bq  = (const float*)d_in[4];
    const float* Wk  = (const float*)d_in[5];
    const float* bk  = (const float*)d_in[6];
    const float* Wv  = (const float*)d_in[7];
    const float* bv  = (const float*)d_in[8];
    const float* Wqp = (const float*)d_in[9];
    const float* bqp = (const float*)d_in[10];
    const float* Wkp = (const float*)d_in[11];
    const float* bkp = (const float*)d_in[12];
    const float* Wvp = (const float*)d_in[13];
    const float* bvp = (const float*)d_in[14];
    const float* Wb  = (const float*)d_in[15];
    const float* bb  = (const float*)d_in[16];
    const float* Wo  = (const float*)d_in[17];
    const float* bo  = (const float*)d_in[18];
    const float* hw  = (const float*)d_in[19];
    float* ws  = (float*)d_ws;
    float* out = (float*)d_out;

    pack_bias<<<2755, 256, 0, stream>>>(s, z, Wq, bq, Wk, bk, Wv, bv,
                                        Wqp, bqp, Wkp, bkp, Wvp, bvp, Wb, bb, Wo, ws);
    proj_mfma<<<dim3(18, 12), 256, 0, stream>>>(ws);
    prep_kernel<<<384, 192, 0, stream>>>(T, hw, ws);
    logits_out40<<<dim3(48, 12), 512, 0, stream>>>(T, ws);
    pairwise_mfma<<<384, 256, 0, stream>>>(z, ws);
    outgemm_mfma<<<dim3(6, 12), 256, 0, stream>>>(ws, bo, out);
}